// Round 7
// baseline (181.294 us; speedup 1.0000x reference)
//
#include <hip/hip_runtime.h>
#include <hip/hip_bf16.h>
#include <stdint.h>

typedef __bf16 bf16_t;
typedef __bf16 bf16x8 __attribute__((ext_vector_type(8)));
typedef float f32x4 __attribute__((ext_vector_type(4)));

#define MFMA_16x16x32(A, B, C) __builtin_amdgcn_mfma_f32_16x16x32_bf16((A), (B), (C), 0, 0, 0)

__device__ inline void gload_lds16(const bf16_t* g, bf16_t* lds) {
  auto* gp = (const __attribute__((address_space(1))) uint32_t*)(uintptr_t)g;
  auto* lp = (__attribute__((address_space(3))) uint32_t*)(uintptr_t)lds;
  __builtin_amdgcn_global_load_lds(gp, lp, 16, 0, 0);
}

// ---------- fp32 -> bf16 elementwise (small weights) ----------
__global__ void k_cvt(const float* __restrict__ in, bf16_t* __restrict__ out, int n) {
  int i = blockIdx.x * blockDim.x + threadIdx.x;
  if (i < n) out[i] = (bf16_t)in[i];
}

// ---------- transpose + cast: in [C][N] f32 -> out [N][C] bf16, per batch (z) ----------
__global__ __launch_bounds__(256)
void k_transpose_cast(const float* __restrict__ in, bf16_t* __restrict__ out, int C, int N) {
  __shared__ float tile[32][33];
  int b = blockIdx.z;
  const float* src = in + (size_t)b * C * N;
  bf16_t* dst = out + (size_t)b * C * N;
  int n0 = blockIdx.x * 32, c0 = blockIdx.y * 32;
  int tx = threadIdx.x, ty = threadIdx.y;
#pragma unroll
  for (int i = 0; i < 32; i += 8)
    tile[ty + i][tx] = src[(size_t)(c0 + ty + i) * N + (n0 + tx)];
  __syncthreads();
#pragma unroll
  for (int i = 0; i < 32; i += 8)
    dst[(size_t)(n0 + ty + i) * C + (c0 + tx)] = (bf16_t)tile[tx][ty + i];
}

// ---------- f_n -> fnT only: read f32 [C][N], write bf16 [N][C], 64x64 tiles ----------
__global__ __launch_bounds__(256)
void k_fnT(const float* __restrict__ in, bf16_t* __restrict__ out_nc, int C, int N) {
  __shared__ float tile[64][65];
  const int b = blockIdx.z;
  const float* src = in + (size_t)b * C * N;
  const int n0 = blockIdx.x * 64, c0 = blockIdx.y * 64;
  const int t = threadIdx.x;
  const int cr = t >> 2;
  const int nc = (t & 3) * 16;
  {
    const float* srow = src + (size_t)(c0 + cr) * N + n0 + nc;
#pragma unroll
    for (int q = 0; q < 4; ++q) {
      float4 v = *(const float4*)(srow + q * 4);
      tile[cr][nc + q * 4 + 0] = v.x; tile[cr][nc + q * 4 + 1] = v.y;
      tile[cr][nc + q * 4 + 2] = v.z; tile[cr][nc + q * 4 + 3] = v.w;
    }
  }
  __syncthreads();
  {
    const int nr = t >> 2;
    const int cc = (t & 3) * 16;
    bf16_t on[16];
#pragma unroll
    for (int q = 0; q < 16; ++q) on[q] = (bf16_t)tile[cc + q][nr];
    bf16_t* dst = out_nc + (size_t)b * (size_t)N * C + (size_t)(n0 + nr) * C + c0 + cc;
    *(uint4*)(dst) = *(uint4*)(on);
    *(uint4*)(dst + 8) = *(uint4*)(on + 8);
  }
}

// ---------- H partials from f32 inputs: Hp[zb][c'][c], zb = b*16+ks ----------
// 128x128 tile, BK=32, reg-staged f32->bf16, split-K=16.
// LDS chunk XOR-swizzle (both write and read): phys_chunk = chunk ^ ((row>>1)&3)
// -> 2-way on ds_write_b128 and ds_read_b128 (2-way is free, m136).
__global__ __launch_bounds__(256)
void k_gram(const float* __restrict__ A, const float* __restrict__ B,
            bf16_t* __restrict__ Cp) {
  // XCD swizzle over 2048 blocks (2048 % 8 == 0 -> bijective)
  int lin = blockIdx.x + 4 * blockIdx.y + 16 * blockIdx.z;
  lin = (lin & 7) * 256 + (lin >> 3);
  const int nt = lin & 3, mt = (lin >> 2) & 3, zb = lin >> 4;  // zb 0..127
  const int b = zb >> 4, ks = zb & 15;
  const float* Ab = A + (size_t)b * 512 * 4096;
  const float* Bb = B + (size_t)b * 512 * 4096;
  const int bm = mt * 128, bn = nt * 128;
  const int kbeg = ks * 256;     // klen = 256 -> 8 steps of BK=32

  const int tid = threadIdx.x;
  const int wave = tid >> 6, lane = tid & 63;
  const int l15 = lane & 15, l4 = lane >> 4;
  const int wm = (wave >> 1) * 64, wn = (wave & 1) * 64;

  __shared__ bf16_t As[128 * 32];
  __shared__ bf16_t Bs[128 * 32];

  f32x4 acc[4][4] = {};

  const int srow = tid >> 1;         // 0..127
  const int scol = (tid & 1) * 16;   // f32 col offset within BK=32
  const int cb = (tid & 1) * 2;      // logical 16B-chunk base (0 or 2)
  const int sw = (srow >> 1) & 3;    // write swizzle
  const int wo0 = srow * 32 + ((cb ^ sw) * 8);        // bf16 elem offsets
  const int wo1 = srow * 32 + (((cb + 1) ^ sw) * 8);
  const int rsw = (l15 >> 1) & 3;    // read swizzle: (row>>1)&3 for row=wm+m*16+l15

  const float* ga = Ab + (size_t)(bm + srow) * 4096 + kbeg + scol;
  const float* gb = Bb + (size_t)(bn + srow) * 4096 + kbeg + scol;

  float4 ra[4], rb[4];
#pragma unroll
  for (int q = 0; q < 4; ++q) {
    ra[q] = *(const float4*)(ga + q * 4);
    rb[q] = *(const float4*)(gb + q * 4);
  }

  for (int i = 0; i < 8; ++i) {
    if (i) __syncthreads();   // prev step's LDS readers done
    bf16_t ta[16], tb[16];
#pragma unroll
    for (int q = 0; q < 4; ++q) {
      ta[q * 4 + 0] = (bf16_t)ra[q].x; ta[q * 4 + 1] = (bf16_t)ra[q].y;
      ta[q * 4 + 2] = (bf16_t)ra[q].z; ta[q * 4 + 3] = (bf16_t)ra[q].w;
      tb[q * 4 + 0] = (bf16_t)rb[q].x; tb[q * 4 + 1] = (bf16_t)rb[q].y;
      tb[q * 4 + 2] = (bf16_t)rb[q].z; tb[q * 4 + 3] = (bf16_t)rb[q].w;
    }
    *(uint4*)(&As[wo0]) = *(uint4*)(ta);
    *(uint4*)(&As[wo1]) = *(uint4*)(ta + 8);
    *(uint4*)(&Bs[wo0]) = *(uint4*)(tb);
    *(uint4*)(&Bs[wo1]) = *(uint4*)(tb + 8);
    if (i + 1 < 8) {  // issue next loads; in flight across barrier + MFMA
      const float* na = ga + (i + 1) * 32;
      const float* nb = gb + (i + 1) * 32;
#pragma unroll
      for (int q = 0; q < 4; ++q) {
        ra[q] = *(const float4*)(na + q * 4);
        rb[q] = *(const float4*)(nb + q * 4);
      }
    }
    __syncthreads();
    bf16x8 af[4], bfr[4];
#pragma unroll
    for (int m = 0; m < 4; ++m)
      af[m] = *(const bf16x8*)(&As[(wm + m * 16 + l15) * 32 + ((l4 ^ rsw) * 8)]);
#pragma unroll
    for (int n = 0; n < 4; ++n)
      bfr[n] = *(const bf16x8*)(&Bs[(wn + n * 16 + l15) * 32 + ((l4 ^ rsw) * 8)]);
#pragma unroll
    for (int m = 0; m < 4; ++m)
#pragma unroll
      for (int n = 0; n < 4; ++n)
        acc[m][n] = MFMA_16x16x32(af[m], bfr[n], acc[m][n]);
  }

  bf16_t* Cb = Cp + (size_t)zb * 262144;
#pragma unroll
  for (int m = 0; m < 4; ++m) {
    const int row0 = wm + m * 16 + l4 * 4;
#pragma unroll
    for (int n = 0; n < 4; ++n) {
      const int col = bn + wn + n * 16 + l15;
#pragma unroll
      for (int j = 0; j < 4; ++j)
        Cb[(size_t)(bm + row0 + j) * 512 + col] = (bf16_t)acc[m][n][j];
    }
  }
}

// ---------- reduce 16 bf16 split-K partials -> bf16 ----------
__global__ __launch_bounds__(256)
void k_reduce16(const bf16_t* __restrict__ p, bf16_t* __restrict__ out) {
  int i = blockIdx.x * blockDim.x + threadIdx.x;  // 262144 threads total
  int b = i >> 15;                 // 32768 threads per batch (SQ/8)
  int e8 = (i & 32767) * 8;
  const bf16_t* pb = p + (size_t)b * 16 * 262144 + e8;
  float s[8] = {};
#pragma unroll
  for (int ks = 0; ks < 16; ++ks) {
    bf16x8 v = *(const bf16x8*)(pb + (size_t)ks * 262144);
#pragma unroll
    for (int j = 0; j < 8; ++j) s[j] += (float)v[j];
  }
  bf16x8 o;
#pragma unroll
  for (int j = 0; j < 8; ++j) o[j] = (bf16_t)s[j];
  *(bf16x8*)(out + (size_t)b * 262144 + e8) = o;
}

// ---------- C[M][N] = A[M][K] * B[N][K]^T  (bf16 in, fp32 acc), dbuf 2-phase ----------
// MODE: 0 = f32 out + bias, 1 = bf16 out
template <int MODE>
__global__ __launch_bounds__(256)
void k_gemm_bt(const bf16_t* __restrict__ A, const bf16_t* __restrict__ B,
               void* __restrict__ Cv, const float* __restrict__ bias,
               int M, int N, int K, int KS,
               long long sA, long long sB, long long sC) {
  const int zb = blockIdx.z;
  const int b = zb / KS, ks = zb - b * KS;
  A += (size_t)b * sA;
  B += (size_t)b * sB;
  const int klen = K / KS;
  const int kbeg = ks * klen;

  const int tid = threadIdx.x;
  const int wave = tid >> 6, lane = tid & 63;
  const int l15 = lane & 15, l4 = lane >> 4;
  const int bm = blockIdx.y * 128, bn = blockIdx.x * 128;
  const int wm = (wave >> 1) * 64, wn = (wave & 1) * 64;

  __shared__ bf16_t As[2][128 * 32];
  __shared__ bf16_t Bs[2][128 * 32];

  f32x4 acc[4][4] = {};

  const int lrow = lane >> 2;
  const int lchunk = (lane & 3) * 8;
  const int ra = wave * 16 + lrow;

  auto stage = [&](int buf, int k0) {
    gload_lds16(&A[(size_t)(bm + ra) * K + k0 + lchunk],      &As[buf][(wave * 16) * 32]);
    gload_lds16(&A[(size_t)(bm + 64 + ra) * K + k0 + lchunk], &As[buf][(64 + wave * 16) * 32]);
    gload_lds16(&B[(size_t)(bn + ra) * K + k0 + lchunk],      &Bs[buf][(wave * 16) * 32]);
    gload_lds16(&B[(size_t)(bn + 64 + ra) * K + k0 + lchunk], &Bs[buf][(64 + wave * 16) * 32]);
  };

  const int nsteps = klen / 32;
  stage(0, kbeg);
  __syncthreads();

  for (int i = 0; i < nsteps; ++i) {
    const int cur = i & 1;
    if (i + 1 < nsteps) stage(cur ^ 1, kbeg + (i + 1) * 32);
    bf16x8 af[4], bfr[4];
#pragma unroll
    for (int m = 0; m < 4; ++m)
      af[m] = *(const bf16x8*)(&As[cur][(wm + m * 16 + l15) * 32 + l4 * 8]);
#pragma unroll
    for (int n = 0; n < 4; ++n)
      bfr[n] = *(const bf16x8*)(&Bs[cur][(wn + n * 16 + l15) * 32 + l4 * 8]);
#pragma unroll
    for (int m = 0; m < 4; ++m)
#pragma unroll
      for (int n = 0; n < 4; ++n)
        acc[m][n] = MFMA_16x16x32(af[m], bfr[n], acc[m][n]);
    __syncthreads();
  }

#pragma unroll
  for (int m = 0; m < 4; ++m) {
    const int row0 = bm + wm + m * 16 + l4 * 4;
#pragma unroll
    for (int n = 0; n < 4; ++n) {
      const int col = bn + wn + n * 16 + l15;
#pragma unroll
      for (int j = 0; j < 4; ++j) {
        float v = acc[m][n][j];
        if (MODE == 1) {
          ((bf16_t*)Cv + (size_t)zb * sC)[(size_t)(row0 + j) * N + col] = (bf16_t)v;
        } else {
          ((float*)Cv + (size_t)zb * sC)[(size_t)(row0 + j) * N + col] = v + bias[row0 + j];
        }
      }
    }
  }
}

// ---------- dots + softmax: one block per (b,h) ----------
__global__ __launch_bounds__(256)
void k_dots_softmax(const bf16_t* __restrict__ T1, const bf16_t* __restrict__ wk,
                    bf16_t* __restrict__ attn) {
  const int bh = blockIdx.x;
  const bf16_t* qh = T1 + (size_t)(bh >> 3) * 262144 + (size_t)(bh & 7) * 64 * 512;
  const bf16_t* kh = wk + (size_t)(bh & 7) * 64 * 512;
  const int tid = threadIdx.x;
  const int wave = tid >> 6, lane = tid & 63;
  const int l15 = lane & 15, l4 = lane >> 4;
  const int wm = (wave >> 1) * 32, wn = (wave & 1) * 32;

  f32x4 acc[2][2] = {};
#pragma unroll 2
  for (int k0 = 0; k0 < 512; k0 += 32) {
    bf16x8 af[2], bfr[2];
#pragma unroll
    for (int m = 0; m < 2; ++m)
      af[m] = *(const bf16x8*)(&qh[(size_t)(wm + m * 16 + l15) * 512 + k0 + l4 * 8]);
#pragma unroll
    for (int n = 0; n < 2; ++n)
      bfr[n] = *(const bf16x8*)(&kh[(size_t)(wn + n * 16 + l15) * 512 + k0 + l4 * 8]);
#pragma unroll
    for (int m = 0; m < 2; ++m)
#pragma unroll
      for (int n = 0; n < 2; ++n)
        acc[m][n] = MFMA_16x16x32(af[m], bfr[n], acc[m][n]);
  }

  __shared__ float S[64][65];
  const float scale = 0.125f;
#pragma unroll
  for (int m = 0; m < 2; ++m)
#pragma unroll
    for (int n = 0; n < 2; ++n)
#pragma unroll
      for (int j = 0; j < 4; ++j)
        S[wm + m * 16 + l4 * 4 + j][wn + n * 16 + l15] = acc[m][n][j] * scale;
  __syncthreads();

  const int r = tid >> 2, seg = (tid & 3) * 16;
  float vals[16];
  float mx = -1e30f;
#pragma unroll
  for (int c = 0; c < 16; ++c) { vals[c] = S[r][seg + c]; mx = fmaxf(mx, vals[c]); }
  mx = fmaxf(mx, __shfl_xor(mx, 1));
  mx = fmaxf(mx, __shfl_xor(mx, 2));
  float sum = 0.f;
#pragma unroll
  for (int c = 0; c < 16; ++c) { vals[c] = __expf(vals[c] - mx); sum += vals[c]; }
  sum += __shfl_xor(sum, 1);
  sum += __shfl_xor(sum, 2);
  const float inv = 1.0f / sum;
  bf16_t* arow = attn + (size_t)bh * 64 * 64 + (size_t)r * 64 + seg;
#pragma unroll
  for (int c = 0; c < 16; ++c) arow[c] = (bf16_t)(vals[c] * inv);
}

// ---------- WvEffT[b][c][h*64+i] = sum_j WvT[h][c][j] * attn[bh][i][j] ----------
__global__ __launch_bounds__(256)
void k_wveff(const bf16_t* __restrict__ wvT, const bf16_t* __restrict__ attn,
             bf16_t* __restrict__ wveffT) {
  const int bh = blockIdx.y;
  const int b = bh >> 3, h = bh & 7;
  const int tid = threadIdx.x;
  const int wave = tid >> 6, lane = tid & 63;
  const int l15 = lane & 15, l4 = lane >> 4;
  const bf16_t* av = wvT + (size_t)h * 512 * 64;
  const bf16_t* ab = attn + (size_t)bh * 64 * 64;
  bf16_t* ob = wveffT + (size_t)b * 262144 + (size_t)h * 64;
  const int cm0 = blockIdx.x * 128;
  const int wm = (wave >> 1) * 64, wn = (wave & 1) * 32;

  f32x4 acc[4][2] = {};
#pragma unroll
  for (int ks = 0; ks < 2; ++ks) {
    const int k0 = ks * 32;
    bf16x8 af[4], bfr[2];
#pragma unroll
    for (int m = 0; m < 4; ++m)
      af[m] = *(const bf16x8*)(&av[(size_t)(cm0 + wm + m * 16 + l15) * 64 + k0 + l4 * 8]);
#pragma unroll
    for (int n = 0; n < 2; ++n)
      bfr[n] = *(const bf16x8*)(&ab[(wn + n * 16 + l15) * 64 + k0 + l4 * 8]);
#pragma unroll
    for (int m = 0; m < 4; ++m)
#pragma unroll
      for (int n = 0; n < 2; ++n)
        acc[m][n] = MFMA_16x16x32(af[m], bfr[n], acc[m][n]);
  }
#pragma unroll
  for (int m = 0; m < 4; ++m)
#pragma unroll
    for (int n = 0; n < 2; ++n)
#pragma unroll
      for (int j = 0; j < 4; ++j)
        ob[(size_t)(cm0 + wm + m * 16 + l4 * 4 + j) * 512 + wn + n * 16 + l15] =
            (bf16_t)acc[m][n][j];
}

extern "C" void kernel_launch(void* const* d_in, const int* in_sizes, int n_in,
                              void* d_out, int out_size, void* d_ws, size_t ws_size,
                              hipStream_t stream) {
  const float* f_m  = (const float*)d_in[0];
  const float* f_n  = (const float*)d_in[1];
  const float* Wq   = (const float*)d_in[2];
  const float* Wkv  = (const float*)d_in[3];
  const float* Wout = (const float*)d_in[4];
  const float* bout = (const float*)d_in[5];
  float* y = (float*)d_out;

  const size_t ACT = (size_t)8 * 4096 * 512;
  const size_t SQ  = (size_t)512 * 512;
  char* p = (char*)d_ws;
  bf16_t* wq_b    = (bf16_t*)p; p += SQ * 2;
  bf16_t* wk_b    = (bf16_t*)p; p += SQ * 2;
  bf16_t* wout_b  = (bf16_t*)p; p += SQ * 2;
  bf16_t* wvT     = (bf16_t*)p; p += SQ * 2;               // [h][c][64]
  bf16_t* attnw   = (bf16_t*)p; p += (size_t)64 * 64 * 64 * 2;
  bf16_t* Hb      = (bf16_t*)p; p += (size_t)8 * SQ * 2;   // [b][c'][c]
  bf16_t* T1      = (bf16_t*)p; p += (size_t)8 * SQ * 2;   // [b][hi][c']
  bf16_t* wveffT  = (bf16_t*)p; p += (size_t)8 * SQ * 2;   // [b][c][hi]
  bf16_t* W2      = (bf16_t*)p; p += (size_t)8 * SQ * 2;   // [b][o][c]
  bf16_t* Hp16    = (bf16_t*)p; p += (size_t)128 * SQ * 2; // bf16 split-16 partials
  bf16_t* fnT     = (bf16_t*)p; p += ACT * 2;              // [b][n][c]

  // weights
  k_cvt<<<dim3((int)(SQ / 256)), 256, 0, stream>>>(Wq, wq_b, (int)SQ);
  k_cvt<<<dim3((int)(SQ / 256)), 256, 0, stream>>>(Wkv, wk_b, (int)SQ);
  k_cvt<<<dim3((int)(SQ / 256)), 256, 0, stream>>>(Wout, wout_b, (int)SQ);
  k_transpose_cast<<<dim3(16, 2, 8), dim3(32, 8), 0, stream>>>(Wkv + SQ, wvT, 64, 512);

  // fnT first (f_n then L3-warm for k_gram)
  k_fnT<<<dim3(64, 8, 8), 256, 0, stream>>>(f_n, fnT, 512, 4096);

  // H from f32 inputs directly (fused cvt), split-K=16, swizzled LDS
  k_gram<<<dim3(4, 4, 128), 256, 0, stream>>>(f_n, f_m, Hp16);
  k_reduce16<<<dim3(1024), 256, 0, stream>>>(Hp16, Hb);

  // T1[b][hi][c'] = sum_c Wq[hi][c] H[b][c'][c]
  k_gemm_bt<1><<<dim3(4, 4, 8), 256, 0, stream>>>(wq_b, Hb, T1, nullptr,
                                                  512, 512, 512, 1,
                                                  0, (long long)SQ, (long long)SQ);
  // dots + softmax -> attn
  k_dots_softmax<<<dim3(64), 256, 0, stream>>>(T1, wk_b, attnw);
  // WvEffT[b][c][hi]
  k_wveff<<<dim3(4, 64), 256, 0, stream>>>(wvT, attnw, wveffT);
  // W2[b][o][c] = sum_hi Wout[o][hi] WvEffT[b][c][hi]
  k_gemm_bt<1><<<dim3(4, 4, 8), 256, 0, stream>>>(wout_b, wveffT, W2, nullptr,
                                                  512, 512, 512, 1,
                                                  0, (long long)SQ, (long long)SQ);
  // y[b][o][n] = sum_c W2[b][o][c] fnT[b][n][c] + bout[o]
  k_gemm_bt<0><<<dim3(32, 4, 8), 256, 0, stream>>>(W2, fnT, y, bout,
                                                   512, 4096, 512, 1,
                                                   (long long)SQ, (long long)ACT / 8,
                                                   (long long)ACT / 8);
}

// Round 8
// 138.665 us; speedup vs baseline: 1.3074x; 1.3074x over previous
//
#include <hip/hip_runtime.h>
#include <hip/hip_bf16.h>
#include <stdint.h>

typedef __bf16 bf16_t;
typedef __bf16 bf16x8 __attribute__((ext_vector_type(8)));
typedef float f32x4 __attribute__((ext_vector_type(4)));

#define MFMA_16x16x32(A, B, C) __builtin_amdgcn_mfma_f32_16x16x32_bf16((A), (B), (C), 0, 0, 0)

__device__ inline void gload_lds16(const bf16_t* g, bf16_t* lds) {
  auto* gp = (const __attribute__((address_space(1))) uint32_t*)(uintptr_t)g;
  auto* lp = (__attribute__((address_space(3))) uint32_t*)(uintptr_t)lds;
  __builtin_amdgcn_global_load_lds(gp, lp, 16, 0, 0);
}

// ---------- fp32 -> bf16 elementwise (small weights) ----------
__global__ void k_cvt(const float* __restrict__ in, bf16_t* __restrict__ out, int n) {
  int i = blockIdx.x * blockDim.x + threadIdx.x;
  if (i < n) out[i] = (bf16_t)in[i];
}

// ---------- transpose + cast: in [C][N] f32 -> out [N][C] bf16, per batch (z) ----------
__global__ __launch_bounds__(256)
void k_transpose_cast(const float* __restrict__ in, bf16_t* __restrict__ out, int C, int N) {
  __shared__ float tile[32][33];
  int b = blockIdx.z;
  const float* src = in + (size_t)b * C * N;
  bf16_t* dst = out + (size_t)b * C * N;
  int n0 = blockIdx.x * 32, c0 = blockIdx.y * 32;
  int tx = threadIdx.x, ty = threadIdx.y;
#pragma unroll
  for (int i = 0; i < 32; i += 8)
    tile[ty + i][tx] = src[(size_t)(c0 + ty + i) * N + (n0 + tx)];
  __syncthreads();
#pragma unroll
  for (int i = 0; i < 32; i += 8)
    dst[(size_t)(n0 + ty + i) * C + (c0 + tx)] = (bf16_t)tile[tx][ty + i];
}

// ---------- f_n -> fnT: read f32 [C][N], write bf16 [N][C], 64x64 tiles ----------
__global__ __launch_bounds__(256)
void k_fnT(const float* __restrict__ in, bf16_t* __restrict__ out_nc, int C, int N) {
  __shared__ float tile[64][65];
  const int b = blockIdx.z;
  const float* src = in + (size_t)b * C * N;
  const int n0 = blockIdx.x * 64, c0 = blockIdx.y * 64;
  const int t = threadIdx.x;
  const int cr = t >> 2;
  const int nc = (t & 3) * 16;
  {
    const float* srow = src + (size_t)(c0 + cr) * N + n0 + nc;
#pragma unroll
    for (int q = 0; q < 4; ++q) {
      float4 v = *(const float4*)(srow + q * 4);
      tile[cr][nc + q * 4 + 0] = v.x; tile[cr][nc + q * 4 + 1] = v.y;
      tile[cr][nc + q * 4 + 2] = v.z; tile[cr][nc + q * 4 + 3] = v.w;
    }
  }
  __syncthreads();
  {
    const int nr = t >> 2;
    const int cc = (t & 3) * 16;
    bf16_t on[16];
#pragma unroll
    for (int q = 0; q < 16; ++q) on[q] = (bf16_t)tile[cc + q][nr];
    bf16_t* dst = out_nc + (size_t)b * (size_t)N * C + (size_t)(n0 + nr) * C + c0 + cc;
    *(uint4*)(dst) = *(uint4*)(on);
    *(uint4*)(dst + 8) = *(uint4*)(on + 8);
  }
}

// ---------- H partials, 256x256 tile, 8 waves, f32-direct reg-staged ----------
// Hp[b*8+ks][c'][c] = sum over n-slice of f_n[c'][n]*f_m[c][n].  BK=32, dbuf,
// one barrier/step.  Swizzle: phys_chunk = chunk ^ ((row>>1)&3), write+read.
__global__ __launch_bounds__(512, 2)
void k_gram256(const float* __restrict__ A, const float* __restrict__ B,
               bf16_t* __restrict__ Cp) {
  const int raw = blockIdx.x;              // 256 blocks
  const int xcd = raw & 7, idx = raw >> 3; // XCD-affine: xcd = batch
  const int mt = idx & 1, nt = (idx >> 1) & 1, pl = idx >> 2;  // pl = ks 0..7
  const int b = xcd, ks = pl;
  const float* Ab = A + (size_t)b * 512 * 4096;
  const float* Bb = B + (size_t)b * 512 * 4096;
  const int bm = mt * 256, bn = nt * 256;
  const int kbeg = ks * 512;               // 16 steps of BK=32

  const int tid = threadIdx.x;
  const int wave = tid >> 6, lane = tid & 63;
  const int l15 = lane & 15, l4 = lane >> 4;
  const int wm = (wave >> 2) * 128, wn = (wave & 3) * 64;
  const int rsw = (l15 >> 1) & 3;          // read swizzle

  __shared__ bf16_t As[2][256 * 32];
  __shared__ bf16_t Bs[2][256 * 32];

  f32x4 acc[8][4] = {};

  // staging: thread -> row rho (0..255), half h (16 f32 = logical chunks 2h,2h+1)
  const int rho = tid >> 1, h = tid & 1;
  const int sw = (rho >> 1) & 3;
  const int wo0 = rho * 32 + (((2 * h) ^ sw) * 8);
  const int wo1 = rho * 32 + (((2 * h + 1) ^ sw) * 8);
  const float* ga = Ab + (size_t)(bm + rho) * 4096 + kbeg + h * 16;
  const float* gb = Bb + (size_t)(bn + rho) * 4096 + kbeg + h * 16;

  float4 ra[4], rb[4];
#pragma unroll
  for (int q = 0; q < 4; ++q) {
    ra[q] = *(const float4*)(ga + q * 4);
    rb[q] = *(const float4*)(gb + q * 4);
  }

  int cur = 0;
  for (int i = 0; i < 16; ++i) {
    bf16_t ta[16], tb[16];
#pragma unroll
    for (int q = 0; q < 4; ++q) {
      ta[q * 4 + 0] = (bf16_t)ra[q].x; ta[q * 4 + 1] = (bf16_t)ra[q].y;
      ta[q * 4 + 2] = (bf16_t)ra[q].z; ta[q * 4 + 3] = (bf16_t)ra[q].w;
      tb[q * 4 + 0] = (bf16_t)rb[q].x; tb[q * 4 + 1] = (bf16_t)rb[q].y;
      tb[q * 4 + 2] = (bf16_t)rb[q].z; tb[q * 4 + 3] = (bf16_t)rb[q].w;
    }
    *(uint4*)(&As[cur][wo0]) = *(uint4*)(ta);
    *(uint4*)(&As[cur][wo1]) = *(uint4*)(ta + 8);
    *(uint4*)(&Bs[cur][wo0]) = *(uint4*)(tb);
    *(uint4*)(&Bs[cur][wo1]) = *(uint4*)(tb + 8);
    if (i + 1 < 16) {  // issue next loads; in flight across barrier+reads+MFMA
      const float* na = ga + (i + 1) * 32;
      const float* nb = gb + (i + 1) * 32;
#pragma unroll
      for (int q = 0; q < 4; ++q) {
        ra[q] = *(const float4*)(na + q * 4);
        rb[q] = *(const float4*)(nb + q * 4);
      }
    }
    __syncthreads();   // single barrier/step: dbuf protects read/write overlap
    bf16x8 bfr[4];
#pragma unroll
    for (int n = 0; n < 4; ++n)
      bfr[n] = *(const bf16x8*)(&Bs[cur][(wn + n * 16 + l15) * 32 + ((l4 ^ rsw) * 8)]);
#pragma unroll
    for (int m = 0; m < 8; ++m) {
      bf16x8 af = *(const bf16x8*)(&As[cur][(wm + m * 16 + l15) * 32 + ((l4 ^ rsw) * 8)]);
#pragma unroll
      for (int n = 0; n < 4; ++n)
        acc[m][n] = MFMA_16x16x32(af, bfr[n], acc[m][n]);
    }
    cur ^= 1;
  }

  bf16_t* Cb = Cp + (size_t)(b * 8 + ks) * 262144;
#pragma unroll
  for (int m = 0; m < 8; ++m) {
    const int row0 = bm + wm + m * 16 + l4 * 4;
#pragma unroll
    for (int n = 0; n < 4; ++n) {
      const int col = bn + wn + n * 16 + l15;
#pragma unroll
      for (int j = 0; j < 4; ++j)
        Cb[(size_t)(row0 + j) * 512 + col] = (bf16_t)acc[m][n][j];
    }
  }
}

// ---------- y GEMM, 256x256 tile, 8 waves, gload_lds w/ pre-swizzled source ----------
// y[b][o][n] = sum_c W2[b][o][c] * fnT[b][n][c] + bias[o]
__global__ __launch_bounds__(512, 2)
void k_y256(const bf16_t* __restrict__ A, const bf16_t* __restrict__ B,
            float* __restrict__ C, const float* __restrict__ bias) {
  const int raw = blockIdx.x;              // 256 blocks
  const int b = raw & 7, c = raw >> 3;     // XCD-affine: xcd = batch
  const int bm = (c & 1) * 256, bn = (c >> 1) * 256;   // M=512, N=4096
  A += (size_t)b * 262144;
  B += (size_t)b * 4096 * 512;
  C += (size_t)b * 512 * 4096;

  const int tid = threadIdx.x;
  const int wave = tid >> 6, lane = tid & 63;
  const int l15 = lane & 15, l4 = lane >> 4;
  const int wm = (wave >> 2) * 128, wn = (wave & 3) * 64;
  const int rsw = (l15 >> 1) & 3;

  __shared__ bf16_t As[2][256 * 32];
  __shared__ bf16_t Bs[2][256 * 32];

  f32x4 acc[8][4] = {};

  // staging: wave w covers rows 32w..32w+31 of both tiles (2 ops each of 16 rows).
  // gload_lds dest is wave-uniform; lane l lands at row rbase+(l>>2), phys chunk l&3.
  // Source pre-swizzle: logical chunk = (l&3) ^ ((l>>3)&3)  [= phys ^ ((row>>1)&3)].
  const int lrow = lane >> 2;
  const int lch = (lane & 3) ^ ((lane >> 3) & 3);
  const bf16_t* srcA = A + (size_t)(bm + wave * 32 + lrow) * 512 + lch * 8;
  const bf16_t* srcB = B + (size_t)(bn + wave * 32 + lrow) * 512 + lch * 8;
  bf16_t* dstA = &As[0][wave * 32 * 32];
  bf16_t* dstB = &Bs[0][wave * 32 * 32];
  const int bufoff = 256 * 32;

  auto stage = [&](int buf, int k0) {
    gload_lds16(srcA + k0,            dstA + buf * bufoff);
    gload_lds16(srcA + 16 * 512 + k0, dstA + buf * bufoff + 512);
    gload_lds16(srcB + k0,            dstB + buf * bufoff);
    gload_lds16(srcB + 16 * 512 + k0, dstB + buf * bufoff + 512);
  };

  stage(0, 0);
  __syncthreads();

  int cur = 0;
  for (int i = 0; i < 16; ++i) {
    if (i + 1 < 16) stage(cur ^ 1, (i + 1) * 32);
    bf16x8 bfr[4];
#pragma unroll
    for (int n = 0; n < 4; ++n)
      bfr[n] = *(const bf16x8*)(&Bs[cur][(wn + n * 16 + l15) * 32 + ((l4 ^ rsw) * 8)]);
#pragma unroll
    for (int m = 0; m < 8; ++m) {
      bf16x8 af = *(const bf16x8*)(&As[cur][(wm + m * 16 + l15) * 32 + ((l4 ^ rsw) * 8)]);
#pragma unroll
      for (int n = 0; n < 4; ++n)
        acc[m][n] = MFMA_16x16x32(af, bfr[n], acc[m][n]);
    }
    __syncthreads();   // drains vmcnt -> next buf staged; all reads of cur done
    cur ^= 1;
  }

#pragma unroll
  for (int m = 0; m < 8; ++m) {
    const int row0 = bm + wm + m * 16 + l4 * 4;
#pragma unroll
    for (int n = 0; n < 4; ++n) {
      const int col = bn + wn + n * 16 + l15;
#pragma unroll
      for (int j = 0; j < 4; ++j)
        C[(size_t)(row0 + j) * 4096 + col] = acc[m][n][j] + bias[row0 + j];
    }
  }
}

// ---------- reduce 8 bf16 split-K partials -> bf16 ----------
__global__ __launch_bounds__(256)
void k_reduce8(const bf16_t* __restrict__ p, bf16_t* __restrict__ out) {
  int i = blockIdx.x * blockDim.x + threadIdx.x;  // 262144 threads
  int b = i >> 15;
  int e8 = (i & 32767) * 8;
  const bf16_t* pb = p + (size_t)b * 8 * 262144 + e8;
  float s[8] = {};
#pragma unroll
  for (int ks = 0; ks < 8; ++ks) {
    bf16x8 v = *(const bf16x8*)(pb + (size_t)ks * 262144);
#pragma unroll
    for (int j = 0; j < 8; ++j) s[j] += (float)v[j];
  }
  bf16x8 o;
#pragma unroll
  for (int j = 0; j < 8; ++j) o[j] = (bf16_t)s[j];
  *(bf16x8*)(out + (size_t)b * 262144 + e8) = o;
}

// ---------- small GEMM C[M][N] = A[M][K] B[N][K]^T, 128x128, dbuf (bf16 out) ----------
__global__ __launch_bounds__(256)
void k_gemm_bt(const bf16_t* __restrict__ A, const bf16_t* __restrict__ B,
               bf16_t* __restrict__ Cv, int M, int N, int K,
               long long sA, long long sB, long long sC) {
  const int zb = blockIdx.z;
  A += (size_t)zb * sA;
  B += (size_t)zb * sB;

  const int tid = threadIdx.x;
  const int wave = tid >> 6, lane = tid & 63;
  const int l15 = lane & 15, l4 = lane >> 4;
  const int bm = blockIdx.y * 128, bn = blockIdx.x * 128;
  const int wm = (wave >> 1) * 64, wn = (wave & 1) * 64;

  __shared__ bf16_t As[2][128 * 32];
  __shared__ bf16_t Bs[2][128 * 32];

  f32x4 acc[4][4] = {};

  const int lrow = lane >> 2;
  const int lchunk = (lane & 3) * 8;
  const int ra = wave * 16 + lrow;

  auto stage = [&](int buf, int k0) {
    gload_lds16(&A[(size_t)(bm + ra) * K + k0 + lchunk],      &As[buf][(wave * 16) * 32]);
    gload_lds16(&A[(size_t)(bm + 64 + ra) * K + k0 + lchunk], &As[buf][(64 + wave * 16) * 32]);
    gload_lds16(&B[(size_t)(bn + ra) * K + k0 + lchunk],      &Bs[buf][(wave * 16) * 32]);
    gload_lds16(&B[(size_t)(bn + 64 + ra) * K + k0 + lchunk], &Bs[buf][(64 + wave * 16) * 32]);
  };

  const int nsteps = K / 32;
  stage(0, 0);
  __syncthreads();

  for (int i = 0; i < nsteps; ++i) {
    const int cur = i & 1;
    if (i + 1 < nsteps) stage(cur ^ 1, (i + 1) * 32);
    bf16x8 af[4], bfr[4];
#pragma unroll
    for (int m = 0; m < 4; ++m)
      af[m] = *(const bf16x8*)(&As[cur][(wm + m * 16 + l15) * 32 + l4 * 8]);
#pragma unroll
    for (int n = 0; n < 4; ++n)
      bfr[n] = *(const bf16x8*)(&Bs[cur][(wn + n * 16 + l15) * 32 + l4 * 8]);
#pragma unroll
    for (int m = 0; m < 4; ++m)
#pragma unroll
      for (int n = 0; n < 4; ++n)
        acc[m][n] = MFMA_16x16x32(af[m], bfr[n], acc[m][n]);
    __syncthreads();
  }

#pragma unroll
  for (int m = 0; m < 4; ++m) {
    const int row0 = bm + wm + m * 16 + l4 * 4;
#pragma unroll
    for (int n = 0; n < 4; ++n) {
      const int col = bn + wn + n * 16 + l15;
#pragma unroll
      for (int j = 0; j < 4; ++j)
        (Cv + (size_t)zb * sC)[(size_t)(row0 + j) * N + col] = (bf16_t)acc[m][n][j];
    }
  }
}

// ---------- dots + softmax: one block per (b,h) ----------
__global__ __launch_bounds__(256)
void k_dots_softmax(const bf16_t* __restrict__ T1, const bf16_t* __restrict__ wk,
                    bf16_t* __restrict__ attn) {
  const int bh = blockIdx.x;
  const bf16_t* qh = T1 + (size_t)(bh >> 3) * 262144 + (size_t)(bh & 7) * 64 * 512;
  const bf16_t* kh = wk + (size_t)(bh & 7) * 64 * 512;
  const int tid = threadIdx.x;
  const int wave = tid >> 6, lane = tid & 63;
  const int l15 = lane & 15, l4 = lane >> 4;
  const int wm = (wave >> 1) * 32, wn = (wave & 1) * 32;

  f32x4 acc[2][2] = {};
#pragma unroll 2
  for (int k0 = 0; k0 < 512; k0 += 32) {
    bf16x8 af[2], bfr[2];
#pragma unroll
    for (int m = 0; m < 2; ++m)
      af[m] = *(const bf16x8*)(&qh[(size_t)(wm + m * 16 + l15) * 512 + k0 + l4 * 8]);
#pragma unroll
    for (int n = 0; n < 2; ++n)
      bfr[n] = *(const bf16x8*)(&kh[(size_t)(wn + n * 16 + l15) * 512 + k0 + l4 * 8]);
#pragma unroll
    for (int m = 0; m < 2; ++m)
#pragma unroll
      for (int n = 0; n < 2; ++n)
        acc[m][n] = MFMA_16x16x32(af[m], bfr[n], acc[m][n]);
  }

  __shared__ float S[64][65];
  const float scale = 0.125f;
#pragma unroll
  for (int m = 0; m < 2; ++m)
#pragma unroll
    for (int n = 0; n < 2; ++n)
#pragma unroll
      for (int j = 0; j < 4; ++j)
        S[wm + m * 16 + l4 * 4 + j][wn + n * 16 + l15] = acc[m][n][j] * scale;
  __syncthreads();

  const int r = tid >> 2, seg = (tid & 3) * 16;
  float vals[16];
  float mx = -1e30f;
#pragma unroll
  for (int c = 0; c < 16; ++c) { vals[c] = S[r][seg + c]; mx = fmaxf(mx, vals[c]); }
  mx = fmaxf(mx, __shfl_xor(mx, 1));
  mx = fmaxf(mx, __shfl_xor(mx, 2));
  float sum = 0.f;
#pragma unroll
  for (int c = 0; c < 16; ++c) { vals[c] = __expf(vals[c] - mx); sum += vals[c]; }
  sum += __shfl_xor(sum, 1);
  sum += __shfl_xor(sum, 2);
  const float inv = 1.0f / sum;
  bf16_t* arow = attn + (size_t)bh * 64 * 64 + (size_t)r * 64 + seg;
#pragma unroll
  for (int c = 0; c < 16; ++c) arow[c] = (bf16_t)(vals[c] * inv);
}

// ---------- WvEffT[b][c][h*64+i] = sum_j WvT[h][c][j] * attn[bh][i][j] ----------
__global__ __launch_bounds__(256)
void k_wveff(const bf16_t* __restrict__ wvT, const bf16_t* __restrict__ attn,
             bf16_t* __restrict__ wveffT) {
  const int bh = blockIdx.y;
  const int b = bh >> 3, h = bh & 7;
  const int tid = threadIdx.x;
  const int wave = tid >> 6, lane = tid & 63;
  const int l15 = lane & 15, l4 = lane >> 4;
  const bf16_t* av = wvT + (size_t)h * 512 * 64;
  const bf16_t* ab = attn + (size_t)bh * 64 * 64;
  bf16_t* ob = wveffT + (size_t)b * 262144 + (size_t)h * 64;
  const int cm0 = blockIdx.x * 128;
  const int wm = (wave >> 1) * 64, wn = (wave & 1) * 32;

  f32x4 acc[4][2] = {};
#pragma unroll
  for (int ks = 0; ks < 2; ++ks) {
    const int k0 = ks * 32;
    bf16x8 af[4], bfr[2];
#pragma unroll
    for (int m = 0; m < 4; ++m)
      af[m] = *(const bf16x8*)(&av[(size_t)(cm0 + wm + m * 16 + l15) * 64 + k0 + l4 * 8]);
#pragma unroll
    for (int n = 0; n < 2; ++n)
      bfr[n] = *(const bf16x8*)(&ab[(wn + n * 16 + l15) * 64 + k0 + l4 * 8]);
#pragma unroll
    for (int m = 0; m < 4; ++m)
#pragma unroll
      for (int n = 0; n < 2; ++n)
        acc[m][n] = MFMA_16x16x32(af[m], bfr[n], acc[m][n]);
  }
#pragma unroll
  for (int m = 0; m < 4; ++m)
#pragma unroll
    for (int n = 0; n < 2; ++n)
#pragma unroll
      for (int j = 0; j < 4; ++j)
        ob[(size_t)(cm0 + wm + m * 16 + l4 * 4 + j) * 512 + wn + n * 16 + l15] =
            (bf16_t)acc[m][n][j];
}

extern "C" void kernel_launch(void* const* d_in, const int* in_sizes, int n_in,
                              void* d_out, int out_size, void* d_ws, size_t ws_size,
                              hipStream_t stream) {
  const float* f_m  = (const float*)d_in[0];
  const float* f_n  = (const float*)d_in[1];
  const float* Wq   = (const float*)d_in[2];
  const float* Wkv  = (const float*)d_in[3];
  const float* Wout = (const float*)d_in[4];
  const float* bout = (const float*)d_in[5];
  float* y = (float*)d_out;

  const size_t ACT = (size_t)8 * 4096 * 512;
  const size_t SQ  = (size_t)512 * 512;
  char* p = (char*)d_ws;
  bf16_t* wq_b    = (bf16_t*)p; p += SQ * 2;
  bf16_t* wk_b    = (bf16_t*)p; p += SQ * 2;
  bf16_t* wout_b  = (bf16_t*)p; p += SQ * 2;
  bf16_t* wvT     = (bf16_t*)p; p += SQ * 2;               // [h][c][64]
  bf16_t* attnw   = (bf16_t*)p; p += (size_t)64 * 64 * 64 * 2;
  bf16_t* Hb      = (bf16_t*)p; p += (size_t)8 * SQ * 2;   // [b][c'][c]
  bf16_t* T1      = (bf16_t*)p; p += (size_t)8 * SQ * 2;   // [b][hi][c']
  bf16_t* wveffT  = (bf16_t*)p; p += (size_t)8 * SQ * 2;   // [b][c][hi]
  bf16_t* W2      = (bf16_t*)p; p += (size_t)8 * SQ * 2;   // [b][o][c]
  bf16_t* Hp8     = (bf16_t*)p; p += (size_t)64 * SQ * 2;  // bf16 split-8 partials
  bf16_t* fnT     = (bf16_t*)p; p += ACT * 2;              // [b][n][c]

  // weights
  k_cvt<<<dim3((int)(SQ / 256)), 256, 0, stream>>>(Wq, wq_b, (int)SQ);
  k_cvt<<<dim3((int)(SQ / 256)), 256, 0, stream>>>(Wkv, wk_b, (int)SQ);
  k_cvt<<<dim3((int)(SQ / 256)), 256, 0, stream>>>(Wout, wout_b, (int)SQ);
  k_transpose_cast<<<dim3(16, 2, 8), dim3(32, 8), 0, stream>>>(Wkv + SQ, wvT, 64, 512);

  // fnT (f_n then L3-warm for k_gram256)
  k_fnT<<<dim3(64, 8, 8), 256, 0, stream>>>(f_n, fnT, 512, 4096);

  // H from f32 inputs, 256^2 tiles, split-K=8
  k_gram256<<<dim3(256), 512, 0, stream>>>(f_n, f_m, Hp8);
  k_reduce8<<<dim3(1024), 256, 0, stream>>>(Hp8, Hb);

  // T1[b][hi][c'] = sum_c Wq[hi][c] H[b][c'][c]
  k_gemm_bt<<<dim3(4, 4, 8), 256, 0, stream>>>(wq_b, Hb, T1, 512, 512, 512,
                                               0, (long long)SQ, (long long)SQ);
  // dots + softmax -> attn
  k_dots_softmax<<<dim3(64), 256, 0, stream>>>(T1, wk_b, attnw);
  // WvEffT[b][c][hi]
  k_wveff<<<dim3(4, 64), 256, 0, stream>>>(wvT, attnw, wveffT);
  // W2[b][o][c] = sum_hi Wout[o][hi] WvEffT[b][c][hi]
  k_gemm_bt<<<dim3(4, 4, 8), 256, 0, stream>>>(wout_b, wveffT, W2, 512, 512, 512,
                                               0, (long long)SQ, (long long)SQ);
  // y[b][o][n] = sum_c W2[b][o][c] fnT[b][n][c] + bout[o], 256^2 tiles
  k_y256<<<dim3(256), 512, 0, stream>>>(W2, fnT, y, bout);
}